// Round 2
// baseline (1113.111 us; speedup 1.0000x reference)
//
#include <hip/hip_runtime.h>
#include <hip/hip_bf16.h>

// B=32, H=W=96, D=128, WS=6, SS=3.
// win/tok layout: [set(2)][b(32)][wy(16)][wx(16)][d(128)]  (set0=regular, set1=shifted)
// tok overwrites win in-place (safe: each k_tokproj block stages its 32 rows to
// LDS behind a barrier before writing them back).

#define DEVFN static __device__ __forceinline__

DEVFN float gelu_exact(float x) {
  return 0.5f * x * (1.0f + erff(x * 0.70710678118654752f));
}

// ---------------- Kernel 1: window means (regular + shifted) ----------------
// grid = 32*16 blocks (b, band r). Block reads rows (6r .. 6r+8) mod 96.
// Regular windows of band r use local rows 0..5; shifted windows use 3..8.
__global__ __launch_bounds__(256) void k_winmean(const float* __restrict__ h,
                                                 float* __restrict__ win) {
  const int blk = blockIdx.x;
  const int b = blk >> 4;
  const int r = blk & 15;
  const int lane = threadIdx.x & 63;
  const int yg = threadIdx.x >> 6;       // 4 row-groups
  const int d2 = lane << 1;              // each thread owns 2 channels

  int y0, ny;
  switch (yg) {
    case 0:  y0 = 0; ny = 3; break;      // rows 0,1,2  (reg only)
    case 1:  y0 = 3; ny = 2; break;      // rows 3,4    (reg + sh)
    case 2:  y0 = 5; ny = 2; break;      // rows 5,6    (5: reg+sh, 6: sh)
    default: y0 = 7; ny = 2; break;      // rows 7,8    (sh only)
  }

  float racc[32], sacc[32];
  #pragma unroll
  for (int i = 0; i < 32; ++i) { racc[i] = 0.f; sacc[i] = 0.f; }

  for (int yy = 0; yy < ny; ++yy) {
    const int yl = y0 + yy;
    int y = 6 * r + yl; if (y >= 96) y -= 96;
    const float* row = h + ((size_t)(b * 9216 + y * 96) * 128 + d2);
    const bool doR = (yl < 6);
    const bool doS = (yl >= 3);
    #pragma unroll
    for (int x = 0; x < 96; ++x) {
      const float2 v = *reinterpret_cast<const float2*>(row + (size_t)x * 128);
      const int wr = x / 6;                    // compile-time (unrolled)
      const int ws_ = ((x + 93) % 96) / 6;     // shifted-window column
      if (doR) { racc[2 * wr]  += v.x; racc[2 * wr + 1]  += v.y; }
      if (doS) { sacc[2 * ws_] += v.x; sacc[2 * ws_ + 1] += v.y; }
    }
  }

  __shared__ float red[2][16][128];
  if (yg == 0) {
    #pragma unroll
    for (int wx = 0; wx < 16; ++wx) {
      red[0][wx][d2] = racc[2 * wx]; red[0][wx][d2 + 1] = racc[2 * wx + 1];
      red[1][wx][d2] = sacc[2 * wx]; red[1][wx][d2 + 1] = sacc[2 * wx + 1];
    }
  }
  __syncthreads();
  for (int g = 1; g < 4; ++g) {
    if (yg == g) {
      #pragma unroll
      for (int wx = 0; wx < 16; ++wx) {
        red[0][wx][d2] += racc[2 * wx]; red[0][wx][d2 + 1] += racc[2 * wx + 1];
        red[1][wx][d2] += sacc[2 * wx]; red[1][wx][d2 + 1] += sacc[2 * wx + 1];
      }
    }
    __syncthreads();
  }

  // win[s][b][r][wx][d]
  float* outp = win + (size_t)b * 32768 + (size_t)r * 2048;
  const float* redf = &red[0][0][0];
  for (int i = threadIdx.x; i < 4096; i += 256) {
    const int s = i >> 11, rem = i & 2047;
    outp[(size_t)s * 1048576 + rem] = redf[s * 2048 + rem] * (1.f / 36.f);
  }
}

// ------------- shared wave-blocked GEMM + bias + LN + GELU helper -----------
// Wave handles 8 tokens (rows tb..tb+7 of xs); lane owns output cols 2l,2l+1.
DEVFN void wave_block_gemm(const float (*Ws)[128], const float (*xs)[128],
                           int tb, int lane,
                           const float* __restrict__ bias,
                           const float* __restrict__ gam,
                           const float* __restrict__ bet,
                           float (&o0)[8], float (&o1)[8]) {
  const int n0 = lane << 1;
  float a0[8], a1[8];
  #pragma unroll
  for (int t = 0; t < 8; ++t) { a0[t] = 0.f; a1[t] = 0.f; }

  for (int k = 0; k < 128; k += 4) {
    float4 xv[8];
    #pragma unroll
    for (int t = 0; t < 8; ++t)
      xv[t] = *reinterpret_cast<const float4*>(&xs[tb + t][k]);
    #pragma unroll
    for (int kk = 0; kk < 4; ++kk) {
      const float2 wv = *reinterpret_cast<const float2*>(&Ws[k + kk][n0]);
      #pragma unroll
      for (int t = 0; t < 8; ++t) {
        const float xk = (kk == 0) ? xv[t].x : (kk == 1) ? xv[t].y
                        : (kk == 2) ? xv[t].z : xv[t].w;
        a0[t] = fmaf(xk, wv.x, a0[t]);
        a1[t] = fmaf(xk, wv.y, a1[t]);
      }
    }
  }

  const float b0 = bias[n0], b1 = bias[n0 + 1];
  const float g0 = gam[n0],  g1 = gam[n0 + 1];
  const float e0 = bet[n0],  e1 = bet[n0 + 1];
  #pragma unroll
  for (int t = 0; t < 8; ++t) {
    const float v0 = a0[t] + b0, v1 = a1[t] + b1;
    float s = v0 + v1, q = v0 * v0 + v1 * v1;
    #pragma unroll
    for (int m = 1; m < 64; m <<= 1) {
      s += __shfl_xor(s, m, 64);
      q += __shfl_xor(q, m, 64);
    }
    const float mean = s * (1.f / 128.f);
    const float var  = q * (1.f / 128.f) - mean * mean;
    const float inv  = rsqrtf(var + 1e-5f);
    o0[t] = gelu_exact((v0 - mean) * inv * g0 + e0);
    o1[t] = gelu_exact((v1 - mean) * inv * g1 + e1);
  }
}

// ---------------- Kernel 2: token_proj on 16384 window means ----------------
// In-place: tok rows t0..t0+31 overwrite win rows t0..t0+31 (staged via LDS).
__global__ __launch_bounds__(256) void k_tokproj(float* __restrict__ win,
    const float* __restrict__ Wt, const float* __restrict__ bt,
    const float* __restrict__ gt, const float* __restrict__ bgt) {
  __shared__ __align__(16) float Ws[128][128];
  __shared__ __align__(16) float xs[32][128];
  const int t0 = blockIdx.x * 32;

  for (int i = threadIdx.x; i < 4096; i += 256)
    reinterpret_cast<float4*>(&Ws[0][0])[i] = reinterpret_cast<const float4*>(Wt)[i];
  const float4* xin = reinterpret_cast<const float4*>(win + (size_t)t0 * 128);
  for (int i = threadIdx.x; i < 1024; i += 256)
    reinterpret_cast<float4*>(&xs[0][0])[i] = xin[i];
  __syncthreads();

  const int lane = threadIdx.x & 63;
  const int tb = (threadIdx.x >> 6) * 8;
  float o0[8], o1[8];
  wave_block_gemm(Ws, xs, tb, lane, bt, gt, bgt, o0, o1);

  const int n0 = lane << 1;
  #pragma unroll
  for (int t = 0; t < 8; ++t)
    *reinterpret_cast<float2*>(win + (size_t)(t0 + tb + t) * 128 + n0) =
        make_float2(o0[t], o1[t]);
}

// -------- Kernel 3: fuse + out_proj on 3x3-distinct vectors + expand --------
// grid = 32*32 blocks (b, gy). Block handles 32 tokens (gx=0..31), each token
// expands to a 3x3 pixel block: y=3gy+i, x=3gx+j.  OUTPUT: float32.
__global__ __launch_bounds__(256) void k_fuse_out(const float* __restrict__ tok,
    const float* __restrict__ Wf, const float* __restrict__ bfv,
    const float* __restrict__ gf, const float* __restrict__ bgf,
    const float* __restrict__ Wo, const float* __restrict__ bo,
    const float* __restrict__ go, const float* __restrict__ bgo,
    const float* __restrict__ mask, float* __restrict__ out) {
  __shared__ __align__(16) float Ws[128][128];
  __shared__ __align__(16) float xs[32][128];
  const int b  = blockIdx.x >> 5;
  const int gy = blockIdx.x & 31;
  const int wy  = gy >> 1;                    // regular window row
  const int wys = ((gy + 31) & 31) >> 1;      // shifted window row (rolled back)
  const float* t0p = tok + (size_t)b * 32768 + (size_t)wy * 2048;
  const float* t1p = tok + 1048576 + (size_t)b * 32768 + (size_t)wys * 2048;

  for (int i = threadIdx.x; i < 4096; i += 256)
    reinterpret_cast<float4*>(&Ws[0][0])[i] = reinterpret_cast<const float4*>(Wf)[i];
  for (int i = threadIdx.x; i < 4096; i += 256) {
    const int t = i >> 7, d = i & 127;
    const int wx = t >> 1, wxs = ((t + 31) & 31) >> 1;
    xs[t][d] = t0p[wx * 128 + d] + t1p[wxs * 128 + d];  // reg + sh
  }
  __syncthreads();

  const int lane = threadIdx.x & 63;
  const int tb = (threadIdx.x >> 6) * 8;
  const int n0 = lane << 1;

  float c0[8], c1[8];
  wave_block_gemm(Ws, xs, tb, lane, bfv, gf, bgf, c0, c1);  // fuse block
  #pragma unroll
  for (int t = 0; t < 8; ++t) {   // wave writes only its own token rows
    xs[tb + t][n0] = c0[t];
    xs[tb + t][n0 + 1] = c1[t];
  }
  __syncthreads();
  for (int i = threadIdx.x; i < 4096; i += 256)
    reinterpret_cast<float4*>(&Ws[0][0])[i] = reinterpret_cast<const float4*>(Wo)[i];
  __syncthreads();

  float o0[8], o1[8];
  wave_block_gemm(Ws, xs, tb, lane, bo, go, bgo, o0, o1);   // out_proj block

  #pragma unroll
  for (int t = 0; t < 8; ++t) {
    const int gx = tb + t;
    #pragma unroll
    for (int i = 0; i < 3; ++i) {
      const int y = 3 * gy + i;
      #pragma unroll
      for (int j = 0; j < 3; ++j) {
        const int x = 3 * gx + j;
        const size_t pix = (size_t)b * 9216 + (size_t)y * 96 + x;
        const float mv = mask[pix];
        *reinterpret_cast<float2*>(out + pix * 128 + n0) =
            make_float2(o0[t] * mv, o1[t] * mv);
      }
    }
  }
}

extern "C" void kernel_launch(void* const* d_in, const int* in_sizes, int n_in,
                              void* d_out, int out_size, void* d_ws, size_t ws_size,
                              hipStream_t stream) {
  (void)in_sizes; (void)n_in; (void)out_size; (void)ws_size;
  const float* h    = (const float*)d_in[0];
  const float* mask = (const float*)d_in[1];
  const float* Wt   = (const float*)d_in[2];
  const float* bt   = (const float*)d_in[3];
  const float* gt   = (const float*)d_in[4];
  const float* bgt  = (const float*)d_in[5];
  const float* Wf   = (const float*)d_in[6];
  const float* bfv  = (const float*)d_in[7];
  const float* gf   = (const float*)d_in[8];
  const float* bgf  = (const float*)d_in[9];
  const float* Wo   = (const float*)d_in[10];
  const float* bo   = (const float*)d_in[11];
  const float* go   = (const float*)d_in[12];
  const float* bgo  = (const float*)d_in[13];

  float* win = (float*)d_ws;            // 2*32*16*16*128 f32 = 8 MB (tok in-place)
  float* out = (float*)d_out;

  hipLaunchKernelGGL(k_winmean, dim3(512), dim3(256), 0, stream, h, win);
  hipLaunchKernelGGL(k_tokproj, dim3(512), dim3(256), 0, stream,
                     win, Wt, bt, gt, bgt);
  hipLaunchKernelGGL(k_fuse_out, dim3(1024), dim3(256), 0, stream,
                     win, Wf, bfv, gf, bgf, Wo, bo, go, bgo, mask, out);
}

// Round 3
// 199.766 us; speedup vs baseline: 5.5721x; 5.5721x over previous
//
#include <hip/hip_runtime.h>
#include <hip/hip_bf16.h>

// B=32, H=W=96, D=128, WS=6, SS=3.
// win/tok layout: [set(2)][b(32)][wy(16)][wx(16)][d(128)]  (set0=regular, set1=shifted)
// tok overwrites win in-place (safe: each k_tokproj block stages its 64 rows to
// LDS behind a barrier before writing them back).

#define DEVFN static __device__ __forceinline__

DEVFN float gelu_exact(float x) {
  return 0.5f * x * (1.0f + erff(x * 0.70710678118654752f));
}

// ---------------- Kernel 1: window means (regular + shifted) ----------------
// grid = 32*16 blocks (b, band r). Block reads rows (6r .. 6r+8) mod 96.
// Regular windows of band r use local rows 0..5; shifted windows use 3..8.
__global__ __launch_bounds__(256) void k_winmean(const float* __restrict__ h,
                                                 float* __restrict__ win) {
  const int blk = blockIdx.x;
  const int b = blk >> 4;
  const int r = blk & 15;
  const int lane = threadIdx.x & 63;
  const int yg = threadIdx.x >> 6;       // 4 row-groups
  const int d2 = lane << 1;              // each thread owns 2 channels

  int y0, ny;
  switch (yg) {
    case 0:  y0 = 0; ny = 3; break;      // rows 0,1,2  (reg only)
    case 1:  y0 = 3; ny = 2; break;      // rows 3,4    (reg + sh)
    case 2:  y0 = 5; ny = 2; break;      // rows 5,6    (5: reg+sh, 6: sh)
    default: y0 = 7; ny = 2; break;      // rows 7,8    (sh only)
  }

  float racc[32], sacc[32];
  #pragma unroll
  for (int i = 0; i < 32; ++i) { racc[i] = 0.f; sacc[i] = 0.f; }

  for (int yy = 0; yy < ny; ++yy) {
    const int yl = y0 + yy;
    int y = 6 * r + yl; if (y >= 96) y -= 96;
    const float* row = h + ((size_t)(b * 9216 + y * 96) * 128 + d2);
    const bool doR = (yl < 6);
    const bool doS = (yl >= 3);
    #pragma unroll
    for (int x = 0; x < 96; ++x) {
      const float2 v = *reinterpret_cast<const float2*>(row + (size_t)x * 128);
      const int wr = x / 6;                    // compile-time (unrolled)
      const int ws_ = ((x + 93) % 96) / 6;     // shifted-window column
      if (doR) { racc[2 * wr]  += v.x; racc[2 * wr + 1]  += v.y; }
      if (doS) { sacc[2 * ws_] += v.x; sacc[2 * ws_ + 1] += v.y; }
    }
  }

  __shared__ float red[2][16][128];
  if (yg == 0) {
    #pragma unroll
    for (int wx = 0; wx < 16; ++wx) {
      red[0][wx][d2] = racc[2 * wx]; red[0][wx][d2 + 1] = racc[2 * wx + 1];
      red[1][wx][d2] = sacc[2 * wx]; red[1][wx][d2 + 1] = sacc[2 * wx + 1];
    }
  }
  __syncthreads();
  for (int g = 1; g < 4; ++g) {
    if (yg == g) {
      #pragma unroll
      for (int wx = 0; wx < 16; ++wx) {
        red[0][wx][d2] += racc[2 * wx]; red[0][wx][d2 + 1] += racc[2 * wx + 1];
        red[1][wx][d2] += sacc[2 * wx]; red[1][wx][d2 + 1] += sacc[2 * wx + 1];
      }
    }
    __syncthreads();
  }

  // win[s][b][r][wx][d]
  float* outp = win + (size_t)b * 32768 + (size_t)r * 2048;
  const float* redf = &red[0][0][0];
  for (int i = threadIdx.x; i < 4096; i += 256) {
    const int s = i >> 11, rem = i & 2047;
    outp[(size_t)s * 1048576 + rem] = redf[s * 2048 + rem] * (1.f / 36.f);
  }
}

// ------------- shared wave-blocked GEMM + bias + LN + GELU helper -----------
// Wave handles 8 tokens (rows tb..tb+7 of xs); lane owns output cols 2l,2l+1.
// Register-lean: accs (16) + transient w (8) + transient xv (4); k-loop unroll
// capped at 2 so the compiler cannot inflate live ranges into spills.
DEVFN void wave_block_gemm(const float (*Ws)[128], const float (*xs)[128],
                           int tb, int lane,
                           const float* __restrict__ bias,
                           const float* __restrict__ gam,
                           const float* __restrict__ bet,
                           float (&o0)[8], float (&o1)[8]) {
  const int n0 = lane << 1;
  float a0[8], a1[8];
  #pragma unroll
  for (int t = 0; t < 8; ++t) { a0[t] = 0.f; a1[t] = 0.f; }

  #pragma unroll 2
  for (int k = 0; k < 128; k += 4) {
    float2 w0 = *reinterpret_cast<const float2*>(&Ws[k + 0][n0]);
    float2 w1 = *reinterpret_cast<const float2*>(&Ws[k + 1][n0]);
    float2 w2 = *reinterpret_cast<const float2*>(&Ws[k + 2][n0]);
    float2 w3 = *reinterpret_cast<const float2*>(&Ws[k + 3][n0]);
    #pragma unroll
    for (int t = 0; t < 8; ++t) {
      const float4 xv = *reinterpret_cast<const float4*>(&xs[tb + t][k]);
      a0[t] = fmaf(xv.x, w0.x, a0[t]); a1[t] = fmaf(xv.x, w0.y, a1[t]);
      a0[t] = fmaf(xv.y, w1.x, a0[t]); a1[t] = fmaf(xv.y, w1.y, a1[t]);
      a0[t] = fmaf(xv.z, w2.x, a0[t]); a1[t] = fmaf(xv.z, w2.y, a1[t]);
      a0[t] = fmaf(xv.w, w3.x, a0[t]); a1[t] = fmaf(xv.w, w3.y, a1[t]);
    }
  }

  const float b0 = bias[n0], b1 = bias[n0 + 1];
  const float g0 = gam[n0],  g1 = gam[n0 + 1];
  const float e0 = bet[n0],  e1 = bet[n0 + 1];
  #pragma unroll
  for (int t = 0; t < 8; ++t) {
    const float v0 = a0[t] + b0, v1 = a1[t] + b1;
    float s = v0 + v1, q = v0 * v0 + v1 * v1;
    #pragma unroll
    for (int m = 1; m < 64; m <<= 1) {
      s += __shfl_xor(s, m, 64);
      q += __shfl_xor(q, m, 64);
    }
    const float mean = s * (1.f / 128.f);
    const float var  = q * (1.f / 128.f) - mean * mean;
    const float inv  = rsqrtf(var + 1e-5f);
    o0[t] = gelu_exact((v0 - mean) * inv * g0 + e0);
    o1[t] = gelu_exact((v1 - mean) * inv * g1 + e1);
  }
}

// ---------------- Kernel 2: token_proj on 16384 window means ----------------
// 512 threads = 8 waves = 64 tokens/block; grid 256.
// In-place: tok rows t0..t0+63 overwrite win rows t0..t0+63 (staged via LDS).
__global__ __launch_bounds__(512) void k_tokproj(float* __restrict__ win,
    const float* __restrict__ Wt, const float* __restrict__ bt,
    const float* __restrict__ gt, const float* __restrict__ bgt) {
  __shared__ __align__(16) float Ws[128][128];
  __shared__ __align__(16) float xs[64][128];
  const int t0 = blockIdx.x * 64;

  for (int i = threadIdx.x; i < 4096; i += 512)
    reinterpret_cast<float4*>(&Ws[0][0])[i] = reinterpret_cast<const float4*>(Wt)[i];
  const float4* xin = reinterpret_cast<const float4*>(win + (size_t)t0 * 128);
  for (int i = threadIdx.x; i < 2048; i += 512)
    reinterpret_cast<float4*>(&xs[0][0])[i] = xin[i];
  __syncthreads();

  const int lane = threadIdx.x & 63;
  const int tb = (threadIdx.x >> 6) * 8;
  float o0[8], o1[8];
  wave_block_gemm(Ws, xs, tb, lane, bt, gt, bgt, o0, o1);

  const int n0 = lane << 1;
  #pragma unroll
  for (int t = 0; t < 8; ++t)
    *reinterpret_cast<float2*>(win + (size_t)(t0 + tb + t) * 128 + n0) =
        make_float2(o0[t], o1[t]);
}

// -------- Kernel 3: fuse + out_proj on 3x3-distinct vectors + expand --------
// 512 threads = 8 waves = 64 tokens/block; grid = 32*16 (b, m).
// Block covers gy = 2m, 2m+1 (both share regular window row wy=m); token
// t (0..63): gy = 2m + (t>>5), gx = t&31; expands to 3x3 pixels. OUTPUT: f32.
__global__ __launch_bounds__(512) void k_fuse_out(const float* __restrict__ tok,
    const float* __restrict__ Wf, const float* __restrict__ bfv,
    const float* __restrict__ gf, const float* __restrict__ bgf,
    const float* __restrict__ Wo, const float* __restrict__ bo,
    const float* __restrict__ go, const float* __restrict__ bgo,
    const float* __restrict__ mask, float* __restrict__ out) {
  __shared__ __align__(16) float Ws[128][128];
  __shared__ __align__(16) float xs[64][128];
  const int b = blockIdx.x >> 4;
  const int m = blockIdx.x & 15;
  const float* tokR = tok + (size_t)b * 32768 + (size_t)m * 2048;  // reg row m
  const float* tokS = tok + 1048576 + (size_t)b * 32768;

  for (int i = threadIdx.x; i < 4096; i += 512)
    reinterpret_cast<float4*>(&Ws[0][0])[i] = reinterpret_cast<const float4*>(Wf)[i];
  for (int i = threadIdx.x; i < 8192; i += 512) {
    const int t = i >> 7, d = i & 127;
    const int gx = t & 31, gy = 2 * m + (t >> 5);
    const int wx  = gx >> 1;
    const int wxs = ((gx + 31) & 31) >> 1;
    const int wys = ((gy + 31) & 31) >> 1;
    xs[t][d] = tokR[wx * 128 + d] + tokS[(wys * 16 + wxs) * 128 + d];  // reg+sh
  }
  __syncthreads();

  const int lane = threadIdx.x & 63;
  const int tb = (threadIdx.x >> 6) * 8;
  const int n0 = lane << 1;

  float c0[8], c1[8];
  wave_block_gemm(Ws, xs, tb, lane, bfv, gf, bgf, c0, c1);  // fuse block
  #pragma unroll
  for (int t = 0; t < 8; ++t) {   // wave writes only its own token rows
    xs[tb + t][n0] = c0[t];
    xs[tb + t][n0 + 1] = c1[t];
  }
  __syncthreads();
  for (int i = threadIdx.x; i < 4096; i += 512)
    reinterpret_cast<float4*>(&Ws[0][0])[i] = reinterpret_cast<const float4*>(Wo)[i];
  __syncthreads();

  float o0[8], o1[8];
  wave_block_gemm(Ws, xs, tb, lane, bo, go, bgo, o0, o1);   // out_proj block

  #pragma unroll
  for (int t = 0; t < 8; ++t) {
    const int tt = tb + t;
    const int gx = tt & 31, gy = 2 * m + (tt >> 5);
    #pragma unroll
    for (int i = 0; i < 3; ++i) {
      const int y = 3 * gy + i;
      #pragma unroll
      for (int j = 0; j < 3; ++j) {
        const int x = 3 * gx + j;
        const size_t pix = (size_t)b * 9216 + (size_t)y * 96 + x;
        const float mv = mask[pix];
        *reinterpret_cast<float2*>(out + pix * 128 + n0) =
            make_float2(o0[t] * mv, o1[t] * mv);
      }
    }
  }
}

extern "C" void kernel_launch(void* const* d_in, const int* in_sizes, int n_in,
                              void* d_out, int out_size, void* d_ws, size_t ws_size,
                              hipStream_t stream) {
  (void)in_sizes; (void)n_in; (void)out_size; (void)ws_size;
  const float* h    = (const float*)d_in[0];
  const float* mask = (const float*)d_in[1];
  const float* Wt   = (const float*)d_in[2];
  const float* bt   = (const float*)d_in[3];
  const float* gt   = (const float*)d_in[4];
  const float* bgt  = (const float*)d_in[5];
  const float* Wf   = (const float*)d_in[6];
  const float* bfv  = (const float*)d_in[7];
  const float* gf   = (const float*)d_in[8];
  const float* bgf  = (const float*)d_in[9];
  const float* Wo   = (const float*)d_in[10];
  const float* bo   = (const float*)d_in[11];
  const float* go   = (const float*)d_in[12];
  const float* bgo  = (const float*)d_in[13];

  float* win = (float*)d_ws;            // 2*32*16*16*128 f32 = 8 MB (tok in-place)
  float* out = (float*)d_out;

  hipLaunchKernelGGL(k_winmean, dim3(512), dim3(256), 0, stream, h, win);
  hipLaunchKernelGGL(k_tokproj, dim3(256), dim3(512), 0, stream,
                     win, Wt, bt, gt, bgt);
  hipLaunchKernelGGL(k_fuse_out, dim3(512), dim3(512), 0, stream,
                     win, Wf, bfv, gf, bgf, Wo, bo, go, bgo, mask, out);
}

// Round 5
// 145.471 us; speedup vs baseline: 7.6518x; 1.3732x over previous
//
#include <hip/hip_runtime.h>
#include <hip/hip_bf16.h>

// B=32, H=W=96, D=128, WS=6, SS=3.
// win/tok layout: [set(2)][b(32)][wy(16)][wx(16)][d(128)]  (set0=regular, set1=shifted)
// tok overwrites win in-place (safe: each k_tokproj block stages its 64 rows to
// LDS behind a barrier before writing them back). ws usage: 8 MB total.

#define DEVFN static __device__ __forceinline__

DEVFN float gelu_exact(float x) {
  return 0.5f * x * (1.0f + erff(x * 0.70710678118654752f));
}

DEVFN void add4(float4& a, const float4 v) {
  a.x += v.x; a.y += v.y; a.z += v.z; a.w += v.w;
}
DEVFN void fma4(float4& a, const float4 v, float m) {
  a.x = fmaf(v.x, m, a.x); a.y = fmaf(v.y, m, a.y);
  a.z = fmaf(v.z, m, a.z); a.w = fmaf(v.w, m, a.w);
}

// ---------------- Kernel 1: window means via 3x3-tile sums ----------------
// grid = 32*16 (b, band r), 512 threads = 8 waves. Band rows 6r..6r+8 (mod 96)
// = tile-rows {2r, 2r+1, 2r+2}. Wave w owns cols [12w,12w+12) = tile-cols
// 4w..4w+3. Lane: half = lane>>5 picks one of 2 cells/instr, (lane&31)*4 = ch.
// Loads are float4, 1 KB per wave-instruction; acc = 3x4 tile float4 (static
// indices; masked-FMA for the two tile-straddling column pairs j=1, j=4).
// reg win (r,wx) = tiles[0..1][2wx..2wx+1]; sh win = tiles[1..2][2wx+1..2wx+2 mod 32].
__global__ __launch_bounds__(512) void k_winmean(const float* __restrict__ h,
                                                 float* __restrict__ win) {
  __shared__ __align__(16) float tiles[3][32][128];
  const int b = blockIdx.x >> 4;
  const int r = blockIdx.x & 15;
  const int w    = threadIdx.x >> 6;      // wave 0..7
  const int lane = threadIdx.x & 63;
  const int half = lane >> 5;             // 0/1: which of the 2 cols per instr
  const int ch4  = (lane & 31) << 2;      // 4 channels per lane
  const float mlo = half ? 0.f : 1.f;
  const float mhi = 1.f - mlo;

  float4 acc[3][4];
  #pragma unroll
  for (int a = 0; a < 3; ++a)
    #pragma unroll
    for (int t = 0; t < 4; ++t) acc[a][t] = make_float4(0.f, 0.f, 0.f, 0.f);

  #pragma unroll
  for (int yl = 0; yl < 9; ++yl) {
    int y = 6 * r + yl; if (y >= 96) y -= 96;
    const int tr = yl / 3;                // static (unrolled)
    const float* rp =
        h + ((size_t)(b * 9216 + y * 96 + 12 * w + half) * 128 + ch4);
    #pragma unroll
    for (int j = 0; j < 6; ++j) {
      const float4 v = *reinterpret_cast<const float4*>(rp + j * 256);
      // col = 12w + 2j + half; tile-col lo = (2j)/3, hi = (2j+1)/3
      if (j == 0)      add4(acc[tr][0], v);
      else if (j == 2) add4(acc[tr][1], v);
      else if (j == 3) add4(acc[tr][2], v);
      else if (j == 5) add4(acc[tr][3], v);
      else if (j == 1) { fma4(acc[tr][0], v, mlo); fma4(acc[tr][1], v, mhi); }
      else             { fma4(acc[tr][2], v, mlo); fma4(acc[tr][3], v, mhi); }
    }
  }

  #pragma unroll
  for (int a = 0; a < 3; ++a)
    #pragma unroll
    for (int t = 0; t < 4; ++t) {
      float4 s = acc[a][t];
      s.x += __shfl_xor(s.x, 32, 64);
      s.y += __shfl_xor(s.y, 32, 64);
      s.z += __shfl_xor(s.z, 32, 64);
      s.w += __shfl_xor(s.w, 32, 64);
      if (half == 0)
        *reinterpret_cast<float4*>(&tiles[a][4 * w + t][ch4]) = s;
    }
  __syncthreads();

  // Compose both window sets from tiles; win[s][b][r][wx][d].
  for (int i = threadIdx.x; i < 4096; i += 512) {
    const int s = i >> 11, wx = (i >> 7) & 15, d = i & 127;
    float v;
    if (s == 0) {
      v = tiles[0][2 * wx][d] + tiles[0][2 * wx + 1][d] +
          tiles[1][2 * wx][d] + tiles[1][2 * wx + 1][d];
    } else {
      const int cA = 2 * wx + 1, cB = (2 * wx + 2) & 31;
      v = tiles[1][cA][d] + tiles[1][cB][d] +
          tiles[2][cA][d] + tiles[2][cB][d];
    }
    win[(size_t)s * 1048576 + ((size_t)b * 16 + r) * 2048 + wx * 128 + d] =
        v * (1.f / 36.f);
  }
}

// ------------- shared wave-blocked GEMM + bias + LN + GELU helper -----------
// Wave handles 8 tokens (rows tb..tb+7 of xs); lane owns output cols 2l,2l+1.
// Register-lean; k-loop unroll capped at 2 to avoid spills (round-2 lesson).
DEVFN void wave_block_gemm(const float (*Ws)[128], const float (*xs)[128],
                           int tb, int lane,
                           const float* __restrict__ bias,
                           const float* __restrict__ gam,
                           const float* __restrict__ bet,
                           float (&o0)[8], float (&o1)[8]) {
  const int n0 = lane << 1;
  float a0[8], a1[8];
  #pragma unroll
  for (int t = 0; t < 8; ++t) { a0[t] = 0.f; a1[t] = 0.f; }

  #pragma unroll 2
  for (int k = 0; k < 128; k += 4) {
    float2 w0 = *reinterpret_cast<const float2*>(&Ws[k + 0][n0]);
    float2 w1 = *reinterpret_cast<const float2*>(&Ws[k + 1][n0]);
    float2 w2 = *reinterpret_cast<const float2*>(&Ws[k + 2][n0]);
    float2 w3 = *reinterpret_cast<const float2*>(&Ws[k + 3][n0]);
    #pragma unroll
    for (int t = 0; t < 8; ++t) {
      const float4 xv = *reinterpret_cast<const float4*>(&xs[tb + t][k]);
      a0[t] = fmaf(xv.x, w0.x, a0[t]); a1[t] = fmaf(xv.x, w0.y, a1[t]);
      a0[t] = fmaf(xv.y, w1.x, a0[t]); a1[t] = fmaf(xv.y, w1.y, a1[t]);
      a0[t] = fmaf(xv.z, w2.x, a0[t]); a1[t] = fmaf(xv.z, w2.y, a1[t]);
      a0[t] = fmaf(xv.w, w3.x, a0[t]); a1[t] = fmaf(xv.w, w3.y, a1[t]);
    }
  }

  const float b0 = bias[n0], b1 = bias[n0 + 1];
  const float g0 = gam[n0],  g1 = gam[n0 + 1];
  const float e0 = bet[n0],  e1 = bet[n0 + 1];
  #pragma unroll
  for (int t = 0; t < 8; ++t) {
    const float v0 = a0[t] + b0, v1 = a1[t] + b1;
    float s = v0 + v1, q = v0 * v0 + v1 * v1;
    #pragma unroll
    for (int m = 1; m < 64; m <<= 1) {
      s += __shfl_xor(s, m, 64);
      q += __shfl_xor(q, m, 64);
    }
    const float mean = s * (1.f / 128.f);
    const float var  = q * (1.f / 128.f) - mean * mean;
    const float inv  = rsqrtf(var + 1e-5f);
    o0[t] = gelu_exact((v0 - mean) * inv * g0 + e0);
    o1[t] = gelu_exact((v1 - mean) * inv * g1 + e1);
  }
}

// ---------------- Kernel 2: token_proj on 16384 window means ----------------
// 512 threads = 8 waves = 64 tokens/block; grid 256.
// In-place: tok rows t0..t0+63 overwrite win rows t0..t0+63 (staged via LDS).
__global__ __launch_bounds__(512) void k_tokproj(float* __restrict__ win,
    const float* __restrict__ Wt, const float* __restrict__ bt,
    const float* __restrict__ gt, const float* __restrict__ bgt) {
  __shared__ __align__(16) float Ws[128][128];
  __shared__ __align__(16) float xs[64][128];
  const int t0 = blockIdx.x * 64;

  for (int i = threadIdx.x; i < 4096; i += 512)
    reinterpret_cast<float4*>(&Ws[0][0])[i] = reinterpret_cast<const float4*>(Wt)[i];
  const float4* xin = reinterpret_cast<const float4*>(win + (size_t)t0 * 128);
  for (int i = threadIdx.x; i < 2048; i += 512)
    reinterpret_cast<float4*>(&xs[0][0])[i] = xin[i];
  __syncthreads();

  const int lane = threadIdx.x & 63;
  const int tb = (threadIdx.x >> 6) * 8;
  float o0[8], o1[8];
  wave_block_gemm(Ws, xs, tb, lane, bt, gt, bgt, o0, o1);

  const int n0 = lane << 1;
  #pragma unroll
  for (int t = 0; t < 8; ++t)
    *reinterpret_cast<float2*>(win + (size_t)(t0 + tb + t) * 128 + n0) =
        make_float2(o0[t], o1[t]);
}

// -------- Kernel 3: fuse + out_proj on 3x3-distinct vectors + expand --------
// 512 threads = 8 waves = 64 tokens/block; grid = 32*16 (b, m).
// Token t (0..63): gy = 2m + (t>>5), gx = t&31; expands to 3x3 pixels. f32 out.
__global__ __launch_bounds__(512) void k_fuse_out(const float* __restrict__ tok,
    const float* __restrict__ Wf, const float* __restrict__ bfv,
    const float* __restrict__ gf, const float* __restrict__ bgf,
    const float* __restrict__ Wo, const float* __restrict__ bo,
    const float* __restrict__ go, const float* __restrict__ bgo,
    const float* __restrict__ mask, float* __restrict__ out) {
  __shared__ __align__(16) float Ws[128][128];
  __shared__ __align__(16) float xs[64][128];
  const int b = blockIdx.x >> 4;
  const int m = blockIdx.x & 15;
  const float* tokR = tok + (size_t)b * 32768 + (size_t)m * 2048;  // reg row m
  const float* tokS = tok + 1048576 + (size_t)b * 32768;

  for (int i = threadIdx.x; i < 4096; i += 512)
    reinterpret_cast<float4*>(&Ws[0][0])[i] = reinterpret_cast<const float4*>(Wf)[i];
  for (int i = threadIdx.x; i < 8192; i += 512) {
    const int t = i >> 7, d = i & 127;
    const int gx = t & 31, gy = 2 * m + (t >> 5);
    const int wx  = gx >> 1;
    const int wxs = ((gx + 31) & 31) >> 1;
    const int wys = ((gy + 31) & 31) >> 1;
    xs[t][d] = tokR[wx * 128 + d] + tokS[(wys * 16 + wxs) * 128 + d];  // reg+sh
  }
  __syncthreads();

  const int lane = threadIdx.x & 63;
  const int tb = (threadIdx.x >> 6) * 8;
  const int n0 = lane << 1;

  float c0[8], c1[8];
  wave_block_gemm(Ws, xs, tb, lane, bfv, gf, bgf, c0, c1);  // fuse block
  #pragma unroll
  for (int t = 0; t < 8; ++t) {   // wave touches only its own token rows
    xs[tb + t][n0] = c0[t];
    xs[tb + t][n0 + 1] = c1[t];
  }
  __syncthreads();
  for (int i = threadIdx.x; i < 4096; i += 512)
    reinterpret_cast<float4*>(&Ws[0][0])[i] = reinterpret_cast<const float4*>(Wo)[i];
  __syncthreads();

  float o0[8], o1[8];
  wave_block_gemm(Ws, xs, tb, lane, bo, go, bgo, o0, o1);   // out_proj block

  #pragma unroll
  for (int t = 0; t < 8; ++t) {
    const int tt = tb + t;
    const int gx = tt & 31, gy = 2 * m + (tt >> 5);
    #pragma unroll
    for (int i = 0; i < 3; ++i) {
      const int y = 3 * gy + i;
      #pragma unroll
      for (int j = 0; j < 3; ++j) {
        const int x = 3 * gx + j;
        const size_t pix = (size_t)b * 9216 + (size_t)y * 96 + x;
        const float mv = mask[pix];
        *reinterpret_cast<float2*>(out + pix * 128 + n0) =
            make_float2(o0[t] * mv, o1[t] * mv);
      }
    }
  }
}

extern "C" void kernel_launch(void* const* d_in, const int* in_sizes, int n_in,
                              void* d_out, int out_size, void* d_ws, size_t ws_size,
                              hipStream_t stream) {
  (void)in_sizes; (void)n_in; (void)out_size; (void)ws_size;
  const float* h    = (const float*)d_in[0];
  const float* mask = (const float*)d_in[1];
  const float* Wt   = (const float*)d_in[2];
  const float* bt   = (const float*)d_in[3];
  const float* gt   = (const float*)d_in[4];
  const float* bgt  = (const float*)d_in[5];
  const float* Wf   = (const float*)d_in[6];
  const float* bfv  = (const float*)d_in[7];
  const float* gf   = (const float*)d_in[8];
  const float* bgf  = (const float*)d_in[9];
  const float* Wo   = (const float*)d_in[10];
  const float* bo   = (const float*)d_in[11];
  const float* go   = (const float*)d_in[12];
  const float* bgo  = (const float*)d_in[13];

  float* win = (float*)d_ws;            // 8 MB in ws (tok in-place)
  float* out = (float*)d_out;

  hipLaunchKernelGGL(k_winmean, dim3(512), dim3(512), 0, stream, h, win);
  hipLaunchKernelGGL(k_tokproj, dim3(256), dim3(512), 0, stream,
                     win, Wt, bt, gt, bgt);
  hipLaunchKernelGGL(k_fuse_out, dim3(512), dim3(512), 0, stream,
                     win, Wf, bfv, gf, bgf, Wo, bo, go, bgo, mask, out);
}

// Round 6
// 128.210 us; speedup vs baseline: 8.6819x; 1.1346x over previous
//
#include <hip/hip_runtime.h>
#include <hip/hip_bf16.h>

// B=32, H=W=96, D=128, WS=6, SS=3.
// win/tok layout: [set(2)][b(32)][wy(16)][wx(16)][d(128)]  (set0=regular, set1=shifted)
// tok overwrites win in-place (safe: each k_tokproj block stages its 64 rows to
// LDS behind a barrier before writing them back). ws usage: 8 MB total.
// GEMM weights are read straight from global (L1/L2-resident, 128 KB total):
// keeps LDS at 32 KB/block -> 16 waves/CU instead of 8.

#define DEVFN static __device__ __forceinline__

DEVFN float gelu_exact(float x) {
  return 0.5f * x * (1.0f + erff(x * 0.70710678118654752f));
}

DEVFN void add4(float4& a, const float4 v) {
  a.x += v.x; a.y += v.y; a.z += v.z; a.w += v.w;
}
DEVFN void fma4(float4& a, const float4 v, float m) {
  a.x = fmaf(v.x, m, a.x); a.y = fmaf(v.y, m, a.y);
  a.z = fmaf(v.z, m, a.z); a.w = fmaf(v.w, m, a.w);
}

// ---------------- Kernel 1: window means via 3x3-tile sums ----------------
// (unchanged from round 5 — measured ~5.6 TB/s effective, near BW ceiling)
__global__ __launch_bounds__(512) void k_winmean(const float* __restrict__ h,
                                                 float* __restrict__ win) {
  __shared__ __align__(16) float tiles[3][32][128];
  const int b = blockIdx.x >> 4;
  const int r = blockIdx.x & 15;
  const int w    = threadIdx.x >> 6;      // wave 0..7
  const int lane = threadIdx.x & 63;
  const int half = lane >> 5;             // 0/1: which of the 2 cols per instr
  const int ch4  = (lane & 31) << 2;      // 4 channels per lane
  const float mlo = half ? 0.f : 1.f;
  const float mhi = 1.f - mlo;

  float4 acc[3][4];
  #pragma unroll
  for (int a = 0; a < 3; ++a)
    #pragma unroll
    for (int t = 0; t < 4; ++t) acc[a][t] = make_float4(0.f, 0.f, 0.f, 0.f);

  #pragma unroll
  for (int yl = 0; yl < 9; ++yl) {
    int y = 6 * r + yl; if (y >= 96) y -= 96;
    const int tr = yl / 3;                // static (unrolled)
    const float* rp =
        h + ((size_t)(b * 9216 + y * 96 + 12 * w + half) * 128 + ch4);
    #pragma unroll
    for (int j = 0; j < 6; ++j) {
      const float4 v = *reinterpret_cast<const float4*>(rp + j * 256);
      if (j == 0)      add4(acc[tr][0], v);
      else if (j == 2) add4(acc[tr][1], v);
      else if (j == 3) add4(acc[tr][2], v);
      else if (j == 5) add4(acc[tr][3], v);
      else if (j == 1) { fma4(acc[tr][0], v, mlo); fma4(acc[tr][1], v, mhi); }
      else             { fma4(acc[tr][2], v, mlo); fma4(acc[tr][3], v, mhi); }
    }
  }

  #pragma unroll
  for (int a = 0; a < 3; ++a)
    #pragma unroll
    for (int t = 0; t < 4; ++t) {
      float4 s = acc[a][t];
      s.x += __shfl_xor(s.x, 32, 64);
      s.y += __shfl_xor(s.y, 32, 64);
      s.z += __shfl_xor(s.z, 32, 64);
      s.w += __shfl_xor(s.w, 32, 64);
      if (half == 0)
        *reinterpret_cast<float4*>(&tiles[a][4 * w + t][ch4]) = s;
    }
  __syncthreads();

  for (int i = threadIdx.x; i < 4096; i += 512) {
    const int s = i >> 11, wx = (i >> 7) & 15, d = i & 127;
    float v;
    if (s == 0) {
      v = tiles[0][2 * wx][d] + tiles[0][2 * wx + 1][d] +
          tiles[1][2 * wx][d] + tiles[1][2 * wx + 1][d];
    } else {
      const int cA = 2 * wx + 1, cB = (2 * wx + 2) & 31;
      v = tiles[1][cA][d] + tiles[1][cB][d] +
          tiles[2][cA][d] + tiles[2][cB][d];
    }
    win[(size_t)s * 1048576 + ((size_t)b * 16 + r) * 2048 + wx * 128 + d] =
        v * (1.f / 36.f);
  }
}

// ---- wave-blocked GEMM + bias + LN + GELU, W streamed from global ----
// Wave handles 8 tokens (rows tb..tb+7 of xs, wave-uniform broadcast reads);
// lane owns output cols 2l,2l+1; W rows read as float2/lane (512 B/wave,
// L1-reused across the block's 8 waves). Unroll capped at 2 (spill lesson).
DEVFN void wave_block_gemm_g(const float* __restrict__ W, const float (*xs)[128],
                             int tb, int lane,
                             const float* __restrict__ bias,
                             const float* __restrict__ gam,
                             const float* __restrict__ bet,
                             float (&o0)[8], float (&o1)[8]) {
  const int n0 = lane << 1;
  const float* wp = W + n0;
  float a0[8], a1[8];
  #pragma unroll
  for (int t = 0; t < 8; ++t) { a0[t] = 0.f; a1[t] = 0.f; }

  #pragma unroll 2
  for (int k = 0; k < 128; k += 4) {
    float2 w0 = *reinterpret_cast<const float2*>(wp + (size_t)(k + 0) * 128);
    float2 w1 = *reinterpret_cast<const float2*>(wp + (size_t)(k + 1) * 128);
    float2 w2 = *reinterpret_cast<const float2*>(wp + (size_t)(k + 2) * 128);
    float2 w3 = *reinterpret_cast<const float2*>(wp + (size_t)(k + 3) * 128);
    #pragma unroll
    for (int t = 0; t < 8; ++t) {
      const float4 xv = *reinterpret_cast<const float4*>(&xs[tb + t][k]);
      a0[t] = fmaf(xv.x, w0.x, a0[t]); a1[t] = fmaf(xv.x, w0.y, a1[t]);
      a0[t] = fmaf(xv.y, w1.x, a0[t]); a1[t] = fmaf(xv.y, w1.y, a1[t]);
      a0[t] = fmaf(xv.z, w2.x, a0[t]); a1[t] = fmaf(xv.z, w2.y, a1[t]);
      a0[t] = fmaf(xv.w, w3.x, a0[t]); a1[t] = fmaf(xv.w, w3.y, a1[t]);
    }
  }

  const float b0 = bias[n0], b1 = bias[n0 + 1];
  const float g0 = gam[n0],  g1 = gam[n0 + 1];
  const float e0 = bet[n0],  e1 = bet[n0 + 1];
  #pragma unroll
  for (int t = 0; t < 8; ++t) {
    const float v0 = a0[t] + b0, v1 = a1[t] + b1;
    float s = v0 + v1, q = v0 * v0 + v1 * v1;
    #pragma unroll
    for (int m = 1; m < 64; m <<= 1) {
      s += __shfl_xor(s, m, 64);
      q += __shfl_xor(q, m, 64);
    }
    const float mean = s * (1.f / 128.f);
    const float var  = q * (1.f / 128.f) - mean * mean;
    const float inv  = rsqrtf(var + 1e-5f);
    o0[t] = gelu_exact((v0 - mean) * inv * g0 + e0);
    o1[t] = gelu_exact((v1 - mean) * inv * g1 + e1);
  }
}

// ---------------- Kernel 2: token_proj on 16384 window means ----------------
// 512 threads = 8 waves = 64 tokens/block; grid 256. LDS: xs only (32 KB).
// In-place: tok rows t0..t0+63 overwrite win rows t0..t0+63 (staged via LDS).
__global__ __launch_bounds__(512) void k_tokproj(float* __restrict__ win,
    const float* __restrict__ Wt, const float* __restrict__ bt,
    const float* __restrict__ gt, const float* __restrict__ bgt) {
  __shared__ __align__(16) float xs[64][128];
  const int t0 = blockIdx.x * 64;

  const float4* xin = reinterpret_cast<const float4*>(win + (size_t)t0 * 128);
  for (int i = threadIdx.x; i < 2048; i += 512)
    reinterpret_cast<float4*>(&xs[0][0])[i] = xin[i];
  __syncthreads();

  const int lane = threadIdx.x & 63;
  const int tb = (threadIdx.x >> 6) * 8;
  float o0[8], o1[8];
  wave_block_gemm_g(Wt, xs, tb, lane, bt, gt, bgt, o0, o1);

  const int n0 = lane << 1;
  #pragma unroll
  for (int t = 0; t < 8; ++t)
    *reinterpret_cast<float2*>(win + (size_t)(t0 + tb + t) * 128 + n0) =
        make_float2(o0[t], o1[t]);
}

// -------- Kernel 3: fuse + out_proj on 3x3-distinct vectors + expand --------
// 512 threads = 8 waves = 64 tokens/block; grid = 32*16 (b, m). LDS: 32 KB.
// ONE barrier (after gather); ctx write-back between GEMMs touches only the
// wave's own 8 rows -> wave-synchronous LDS, no cross-wave barrier needed.
__global__ __launch_bounds__(512) void k_fuse_out(const float* __restrict__ tok,
    const float* __restrict__ Wf, const float* __restrict__ bfv,
    const float* __restrict__ gf, const float* __restrict__ bgf,
    const float* __restrict__ Wo, const float* __restrict__ bo,
    const float* __restrict__ go, const float* __restrict__ bgo,
    const float* __restrict__ mask, float* __restrict__ out) {
  __shared__ __align__(16) float xs[64][128];
  const int b = blockIdx.x >> 4;
  const int m = blockIdx.x & 15;
  const float* tokR = tok + (size_t)b * 32768 + (size_t)m * 2048;  // reg row m
  const float* tokS = tok + 1048576 + (size_t)b * 32768;

  for (int i = threadIdx.x; i < 2048; i += 512) {
    const int t = i >> 5, d4 = (i & 31) << 2;
    const int gx = t & 31, gy = 2 * m + (t >> 5);
    const int wx  = gx >> 1;
    const int wxs = ((gx + 31) & 31) >> 1;
    const int wys = ((gy + 31) & 31) >> 1;
    const float4 vr = *reinterpret_cast<const float4*>(tokR + (size_t)wx * 128 + d4);
    const float4 vs = *reinterpret_cast<const float4*>(tokS + (size_t)(wys * 16 + wxs) * 128 + d4);
    *reinterpret_cast<float4*>(&xs[t][d4]) =
        make_float4(vr.x + vs.x, vr.y + vs.y, vr.z + vs.z, vr.w + vs.w);
  }
  __syncthreads();

  const int lane = threadIdx.x & 63;
  const int tb = (threadIdx.x >> 6) * 8;
  const int n0 = lane << 1;

  float c0[8], c1[8];
  wave_block_gemm_g(Wf, xs, tb, lane, bfv, gf, bgf, c0, c1);  // fuse block
  #pragma unroll
  for (int t = 0; t < 8; ++t) {   // wave-private rows; no barrier needed
    xs[tb + t][n0] = c0[t];
    xs[tb + t][n0 + 1] = c1[t];
  }

  float o0[8], o1[8];
  wave_block_gemm_g(Wo, xs, tb, lane, bo, go, bgo, o0, o1);   // out_proj block

  #pragma unroll
  for (int t = 0; t < 8; ++t) {
    const int tt = tb + t;
    const int gx = tt & 31, gy = 2 * m + (tt >> 5);
    #pragma unroll
    for (int i = 0; i < 3; ++i) {
      const int y = 3 * gy + i;
      #pragma unroll
      for (int j = 0; j < 3; ++j) {
        const int x = 3 * gx + j;
        const size_t pix = (size_t)b * 9216 + (size_t)y * 96 + x;
        const float mv = mask[pix];
        *reinterpret_cast<float2*>(out + pix * 128 + n0) =
            make_float2(o0[t] * mv, o1[t] * mv);
      }
    }
  }
}

extern "C" void kernel_launch(void* const* d_in, const int* in_sizes, int n_in,
                              void* d_out, int out_size, void* d_ws, size_t ws_size,
                              hipStream_t stream) {
  (void)in_sizes; (void)n_in; (void)out_size; (void)ws_size;
  const float* h    = (const float*)d_in[0];
  const float* mask = (const float*)d_in[1];
  const float* Wt   = (const float*)d_in[2];
  const float* bt   = (const float*)d_in[3];
  const float* gt   = (const float*)d_in[4];
  const float* bgt  = (const float*)d_in[5];
  const float* Wf   = (const float*)d_in[6];
  const float* bfv  = (const float*)d_in[7];
  const float* gf   = (const float*)d_in[8];
  const float* bgf  = (const float*)d_in[9];
  const float* Wo   = (const float*)d_in[10];
  const float* bo   = (const float*)d_in[11];
  const float* go   = (const float*)d_in[12];
  const float* bgo  = (const float*)d_in[13];

  float* win = (float*)d_ws;            // 8 MB in ws (tok in-place)
  float* out = (float*)d_out;

  hipLaunchKernelGGL(k_winmean, dim3(512), dim3(512), 0, stream, h, win);
  hipLaunchKernelGGL(k_tokproj, dim3(256), dim3(512), 0, stream,
                     win, Wt, bt, gt, bgt);
  hipLaunchKernelGGL(k_fuse_out, dim3(512), dim3(512), 0, stream,
                     win, Wf, bfv, gf, bgf, Wo, bo, go, bgo, mask, out);
}

// Round 7
// 127.798 us; speedup vs baseline: 8.7099x; 1.0032x over previous
//
#include <hip/hip_runtime.h>
#include <hip/hip_bf16.h>

// B=32, H=W=96, D=128, WS=6, SS=3.
// tok layout: [set(2)][b(32)][wy(16)][wx(16)][d(128)] = 8 MB in d_ws.
// k_wintok: window means via 3x3-tile sums AND token_proj fused (each band
// block owns all 32 tokens it produces). k_fuse_out unchanged from round 6.
// GEMM weights stream from global (L2-resident, 128 KB total); LDS stays lean.

#define DEVFN static __device__ __forceinline__

DEVFN float gelu_exact(float x) {
  return 0.5f * x * (1.0f + erff(x * 0.70710678118654752f));
}

DEVFN void add4(float4& a, const float4 v) {
  a.x += v.x; a.y += v.y; a.z += v.z; a.w += v.w;
}
DEVFN void fma4(float4& a, const float4 v, float m) {
  a.x = fmaf(v.x, m, a.x); a.y = fmaf(v.y, m, a.y);
  a.z = fmaf(v.z, m, a.z); a.w = fmaf(v.w, m, a.w);
}

// ---- wave-blocked GEMM + bias + LN + GELU, W streamed from global ----
// Wave handles T tokens (rows tb..tb+T-1 of xs, wave-uniform broadcast reads);
// lane owns output cols 2l,2l+1. Unroll capped at 2 (round-2 spill lesson).
template <int T>
DEVFN void wave_gemm_ln_gelu(const float* __restrict__ W, const float (*xs)[128],
                             int tb, int lane,
                             const float* __restrict__ bias,
                             const float* __restrict__ gam,
                             const float* __restrict__ bet,
                             float (&o0)[T], float (&o1)[T]) {
  const int n0 = lane << 1;
  const float* wp = W + n0;
  float a0[T], a1[T];
  #pragma unroll
  for (int t = 0; t < T; ++t) { a0[t] = 0.f; a1[t] = 0.f; }

  #pragma unroll 2
  for (int k = 0; k < 128; k += 4) {
    float2 w0 = *reinterpret_cast<const float2*>(wp + (size_t)(k + 0) * 128);
    float2 w1 = *reinterpret_cast<const float2*>(wp + (size_t)(k + 1) * 128);
    float2 w2 = *reinterpret_cast<const float2*>(wp + (size_t)(k + 2) * 128);
    float2 w3 = *reinterpret_cast<const float2*>(wp + (size_t)(k + 3) * 128);
    #pragma unroll
    for (int t = 0; t < T; ++t) {
      const float4 xv = *reinterpret_cast<const float4*>(&xs[tb + t][k]);
      a0[t] = fmaf(xv.x, w0.x, a0[t]); a1[t] = fmaf(xv.x, w0.y, a1[t]);
      a0[t] = fmaf(xv.y, w1.x, a0[t]); a1[t] = fmaf(xv.y, w1.y, a1[t]);
      a0[t] = fmaf(xv.z, w2.x, a0[t]); a1[t] = fmaf(xv.z, w2.y, a1[t]);
      a0[t] = fmaf(xv.w, w3.x, a0[t]); a1[t] = fmaf(xv.w, w3.y, a1[t]);
    }
  }

  const float b0 = bias[n0], b1 = bias[n0 + 1];
  const float g0 = gam[n0],  g1 = gam[n0 + 1];
  const float e0 = bet[n0],  e1 = bet[n0 + 1];
  #pragma unroll
  for (int t = 0; t < T; ++t) {
    const float v0 = a0[t] + b0, v1 = a1[t] + b1;
    float s = v0 + v1, q = v0 * v0 + v1 * v1;
    #pragma unroll
    for (int m = 1; m < 64; m <<= 1) {
      s += __shfl_xor(s, m, 64);
      q += __shfl_xor(q, m, 64);
    }
    const float mean = s * (1.f / 128.f);
    const float var  = q * (1.f / 128.f) - mean * mean;
    const float inv  = rsqrtf(var + 1e-5f);
    o0[t] = gelu_exact((v0 - mean) * inv * g0 + e0);
    o1[t] = gelu_exact((v1 - mean) * inv * g1 + e1);
  }
}

// ------- Kernel 1: window means via 3x3-tile sums + fused token_proj -------
// grid = 32*16 (b, band r), 512 threads = 8 waves. Band rows 6r..6r+8 (mod 96)
// = tile-rows {2r, 2r+1, 2r+2}. Wave w owns cols [12w,12w+12) = tile-cols
// 4w..4w+3; float4 loads, masked-FMA for tile-straddling column pairs.
// reg win (r,wx) = tiles[0..1][2wx..2wx+1]; sh win = tiles[1..2][2wx+1..2wx+2&31].
// Then token_proj GEMM on the 32 composed tokens (4 tokens/wave); xs aliases
// tiles[0] (compose to regs -> barrier -> write back) so LDS stays 48 KB.
__global__ __launch_bounds__(512) void k_wintok(const float* __restrict__ h,
    const float* __restrict__ Wt, const float* __restrict__ bt,
    const float* __restrict__ gt, const float* __restrict__ bgt,
    float* __restrict__ tok) {
  __shared__ __align__(16) float tiles[3][32][128];
  const int b = blockIdx.x >> 4;
  const int r = blockIdx.x & 15;
  const int w    = threadIdx.x >> 6;      // wave 0..7
  const int lane = threadIdx.x & 63;
  const int half = lane >> 5;             // 0/1: which of the 2 cols per instr
  const int ch4  = (lane & 31) << 2;      // 4 channels per lane
  const float mlo = half ? 0.f : 1.f;
  const float mhi = 1.f - mlo;

  float4 acc[3][4];
  #pragma unroll
  for (int a = 0; a < 3; ++a)
    #pragma unroll
    for (int t = 0; t < 4; ++t) acc[a][t] = make_float4(0.f, 0.f, 0.f, 0.f);

  #pragma unroll
  for (int yl = 0; yl < 9; ++yl) {
    int y = 6 * r + yl; if (y >= 96) y -= 96;
    const int tr = yl / 3;                // static (unrolled)
    const float* rp =
        h + ((size_t)(b * 9216 + y * 96 + 12 * w + half) * 128 + ch4);
    #pragma unroll
    for (int j = 0; j < 6; ++j) {
      const float4 v = *reinterpret_cast<const float4*>(rp + j * 256);
      if (j == 0)      add4(acc[tr][0], v);
      else if (j == 2) add4(acc[tr][1], v);
      else if (j == 3) add4(acc[tr][2], v);
      else if (j == 5) add4(acc[tr][3], v);
      else if (j == 1) { fma4(acc[tr][0], v, mlo); fma4(acc[tr][1], v, mhi); }
      else             { fma4(acc[tr][2], v, mlo); fma4(acc[tr][3], v, mhi); }
    }
  }

  #pragma unroll
  for (int a = 0; a < 3; ++a)
    #pragma unroll
    for (int t = 0; t < 4; ++t) {
      float4 s = acc[a][t];
      s.x += __shfl_xor(s.x, 32, 64);
      s.y += __shfl_xor(s.y, 32, 64);
      s.z += __shfl_xor(s.z, 32, 64);
      s.w += __shfl_xor(s.w, 32, 64);
      if (half == 0)
        *reinterpret_cast<float4*>(&tiles[a][4 * w + t][ch4]) = s;
    }
  __syncthreads();

  // Compose 32 window means (16 reg + 16 sh) into registers (8 values/thread).
  float cv[8];
  #pragma unroll
  for (int j = 0; j < 8; ++j) {
    const int i = threadIdx.x + j * 512;   // 0..4095
    const int t = i >> 7, d = i & 127;
    if (t < 16) {
      const int wx = t;
      cv[j] = (tiles[0][2 * wx][d] + tiles[0][2 * wx + 1][d] +
               tiles[1][2 * wx][d] + tiles[1][2 * wx + 1][d]) * (1.f / 36.f);
    } else {
      const int wx = t - 16;
      const int cA = 2 * wx + 1, cB = (2 * wx + 2) & 31;
      cv[j] = (tiles[1][cA][d] + tiles[1][cB][d] +
               tiles[2][cA][d] + tiles[2][cB][d]) * (1.f / 36.f);
    }
  }
  __syncthreads();
  float (*xs)[128] = tiles[0];             // alias: 32x128 fits tiles[0] exactly
  #pragma unroll
  for (int j = 0; j < 8; ++j) {
    const int i = threadIdx.x + j * 512;
    xs[i >> 7][i & 127] = cv[j];
  }
  __syncthreads();

  // token_proj on the 32 tokens: 4 tokens per wave.
  const int tb = w * 4;
  float o0[4], o1[4];
  wave_gemm_ln_gelu<4>(Wt, xs, tb, lane, bt, gt, bgt, o0, o1);

  const int n0 = lane << 1;
  #pragma unroll
  for (int t = 0; t < 4; ++t) {
    const int tt = tb + t;                 // 0..31
    const int s = tt >> 4, wx = tt & 15;
    *reinterpret_cast<float2*>(tok + (size_t)s * 1048576 +
        ((size_t)b * 16 + r) * 2048 + (size_t)wx * 128 + n0) =
        make_float2(o0[t], o1[t]);
  }
}

// -------- Kernel 2: fuse + out_proj on 3x3-distinct vectors + expand --------
// 512 threads = 8 waves = 64 tokens/block; grid = 32*16 (b, m). LDS: 32 KB.
// ONE barrier (after gather); ctx write-back between GEMMs touches only the
// wave's own 8 rows -> wave-synchronous LDS, no cross-wave barrier needed.
__global__ __launch_bounds__(512) void k_fuse_out(const float* __restrict__ tok,
    const float* __restrict__ Wf, const float* __restrict__ bfv,
    const float* __restrict__ gf, const float* __restrict__ bgf,
    const float* __restrict__ Wo, const float* __restrict__ bo,
    const float* __restrict__ go, const float* __restrict__ bgo,
    const float* __restrict__ mask, float* __restrict__ out) {
  __shared__ __align__(16) float xs[64][128];
  const int b = blockIdx.x >> 4;
  const int m = blockIdx.x & 15;
  const float* tokR = tok + (size_t)b * 32768 + (size_t)m * 2048;  // reg row m
  const float* tokS = tok + 1048576 + (size_t)b * 32768;

  for (int i = threadIdx.x; i < 2048; i += 512) {
    const int t = i >> 5, d4 = (i & 31) << 2;
    const int gx = t & 31, gy = 2 * m + (t >> 5);
    const int wx  = gx >> 1;
    const int wxs = ((gx + 31) & 31) >> 1;
    const int wys = ((gy + 31) & 31) >> 1;
    const float4 vr = *reinterpret_cast<const float4*>(tokR + (size_t)wx * 128 + d4);
    const float4 vs = *reinterpret_cast<const float4*>(tokS + (size_t)(wys * 16 + wxs) * 128 + d4);
    *reinterpret_cast<float4*>(&xs[t][d4]) =
        make_float4(vr.x + vs.x, vr.y + vs.y, vr.z + vs.z, vr.w + vs.w);
  }
  __syncthreads();

  const int lane = threadIdx.x & 63;
  const int tb = (threadIdx.x >> 6) * 8;
  const int n0 = lane << 1;

  float c0[8], c1[8];
  wave_gemm_ln_gelu<8>(Wf, xs, tb, lane, bfv, gf, bgf, c0, c1);  // fuse block
  #pragma unroll
  for (int t = 0; t < 8; ++t) {   // wave-private rows; no barrier needed
    xs[tb + t][n0] = c0[t];
    xs[tb + t][n0 + 1] = c1[t];
  }

  float o0[8], o1[8];
  wave_gemm_ln_gelu<8>(Wo, xs, tb, lane, bo, go, bgo, o0, o1);   // out_proj

  #pragma unroll
  for (int t = 0; t < 8; ++t) {
    const int tt = tb + t;
    const int gx = tt & 31, gy = 2 * m + (tt >> 5);
    #pragma unroll
    for (int i = 0; i < 3; ++i) {
      const int y = 3 * gy + i;
      #pragma unroll
      for (int j = 0; j < 3; ++j) {
        const int x = 3 * gx + j;
        const size_t pix = (size_t)b * 9216 + (size_t)y * 96 + x;
        const float mv = mask[pix];
        *reinterpret_cast<float2*>(out + pix * 128 + n0) =
            make_float2(o0[t] * mv, o1[t] * mv);
      }
    }
  }
}

extern "C" void kernel_launch(void* const* d_in, const int* in_sizes, int n_in,
                              void* d_out, int out_size, void* d_ws, size_t ws_size,
                              hipStream_t stream) {
  (void)in_sizes; (void)n_in; (void)out_size; (void)ws_size;
  const float* h    = (const float*)d_in[0];
  const float* mask = (const float*)d_in[1];
  const float* Wt   = (const float*)d_in[2];
  const float* bt   = (const float*)d_in[3];
  const float* gt   = (const float*)d_in[4];
  const float* bgt  = (const float*)d_in[5];
  const float* Wf   = (const float*)d_in[6];
  const float* bfv  = (const float*)d_in[7];
  const float* gf   = (const float*)d_in[8];
  const float* bgf  = (const float*)d_in[9];
  const float* Wo   = (const float*)d_in[10];
  const float* bo   = (const float*)d_in[11];
  const float* go   = (const float*)d_in[12];
  const float* bgo  = (const float*)d_in[13];

  float* tok = (float*)d_ws;            // 8 MB in ws
  float* out = (float*)d_out;

  hipLaunchKernelGGL(k_wintok, dim3(512), dim3(512), 0, stream,
                     h, Wt, bt, gt, bgt, tok);
  hipLaunchKernelGGL(k_fuse_out, dim3(512), dim3(512), 0, stream,
                     tok, Wf, bfv, gf, bgf, Wo, bo, go, bgo, mask, out);
}